// Round 7
// baseline (3078.003 us; speedup 1.0000x reference)
//
#include <hip/hip_runtime.h>

#define NN 100000
#define NE 1600000
#define DIM 64
#define TT 11
#define NB_SCAN 391   // ceil(NN/256)
#define NCH 13        // source chunks of 8192 nodes (src>>13)
#define CST 16        // per-row chunk slot stride

typedef unsigned short u16;
typedef unsigned int u32;

__device__ __forceinline__ u32 pack_bf16(float a, float b) {
    u32 ua = __float_as_uint(a);
    ua += 0x7fff + ((ua >> 16) & 1);
    u32 ub = __float_as_uint(b);
    ub += 0x7fff + ((ub >> 16) & 1);
    return (ua >> 16) | (ub & 0xffff0000u);
}
__device__ __forceinline__ float bf2f(u16 v) {
    return __uint_as_float(((u32)v) << 16);
}

// ---------------- CSR build (chunk-ordered rows) ----------------
__global__ void k_degc(const int* __restrict__ src, const int* __restrict__ dst,
                       int* __restrict__ degc) {
    int e = blockIdx.x * blockDim.x + threadIdx.x;
    if (e < NE) atomicAdd(&degc[dst[e] * CST + (src[e] >> 13)], 1);
}

__global__ __launch_bounds__(256) void k_bsum(const int* __restrict__ degc,
                                              int* __restrict__ bsum) {
    __shared__ int s[256];
    int t = threadIdx.x;
    int i = blockIdx.x * 256 + t;
    int d = 0;
    if (i < NN) {
#pragma unroll
        for (int c = 0; c < NCH; ++c) d += degc[i * CST + c];
    }
    s[t] = d;
    __syncthreads();
    for (int off = 128; off >= 1; off >>= 1) {
        if (t < off) s[t] += s[t + off];
        __syncthreads();
    }
    if (t == 0) bsum[blockIdx.x] = s[0];
}

__global__ __launch_bounds__(512) void k_scan1(const int* __restrict__ bsum,
                                               int* __restrict__ bpre) {
    __shared__ int s[512];
    int t = threadIdx.x;
    int v0 = (t < NB_SCAN) ? bsum[t] : 0;
    s[t] = v0;
    __syncthreads();
    for (int off = 1; off < 512; off <<= 1) {
        int v = (t >= off) ? s[t - off] : 0;
        __syncthreads();
        s[t] += v;
        __syncthreads();
    }
    if (t < NB_SCAN) bpre[t] = s[t] - v0;
}

__global__ __launch_bounds__(256) void k_rowptr(const int* __restrict__ degc,
        const int* __restrict__ bpre, int* __restrict__ row_ptr,
        int* __restrict__ cursor16, u16* __restrict__ ccnt,
        float* __restrict__ deg_inv) {
    __shared__ int s[256];
    int t = threadIdx.x;
    int i = blockIdx.x * 256 + t;
    int dc[NCH];
    int d = 0;
    if (i < NN) {
#pragma unroll
        for (int c = 0; c < NCH; ++c) { dc[c] = degc[i * CST + c]; d += dc[c]; }
    }
    s[t] = d;
    __syncthreads();
    for (int off = 1; off < 256; off <<= 1) {
        int v = (t >= off) ? s[t - off] : 0;
        __syncthreads();
        s[t] += v;
        __syncthreads();
    }
    if (i < NN) {
        int excl = bpre[blockIdx.x] + s[t] - d;
        row_ptr[i] = excl;
        deg_inv[i] = d > 0 ? 1.0f / (float)d : 0.0f;
        int run = excl;
#pragma unroll
        for (int c = 0; c < NCH; ++c) {
            cursor16[i * CST + c] = run;
            ccnt[i * CST + c] = (u16)dc[c];
            run += dc[c];
        }
#pragma unroll
        for (int c = NCH; c < CST; ++c) ccnt[i * CST + c] = 0;
        if (i == NN - 1) row_ptr[NN] = excl + d;
    }
}

__global__ void k_fillc(const int* __restrict__ src, const int* __restrict__ dst,
        int* __restrict__ cursor16, int* __restrict__ csr_src) {
    int e = blockIdx.x * blockDim.x + threadIdx.x;
    if (e < NE) {
        int sv = src[e];
        int p = atomicAdd(&cursor16[dst[e] * CST + (sv >> 13)], 1);
        csr_src[p] = sv;
    }
}

// ---------------- chunk-synchronized mean-aggregate ----------------
// block = 256 thr = 4 waves = 32 rows; 8-lane group per row, lane owns 8 dims.
// All resident rows walk source chunks IN LOCKSTEP (chunk-major time order):
// instantaneous read set ~2 chunks (~2MB bf16) -> per-XCD L2 resident.
__global__ __launch_bounds__(256) void k_gather(const u16* __restrict__ hb,
        const int* __restrict__ row_ptr, const u16* __restrict__ ccnt,
        const int* __restrict__ csr_src, const float* __restrict__ deg_inv,
        u16* __restrict__ Mb) {
    int tid = threadIdx.x;
    int wv = tid >> 6, lane = tid & 63;
    int g = lane >> 3, d4 = lane & 7;
    int row = blockIdx.x * 32 + wv * 8 + g;   // NN = 3125*32 exactly
    int pos = row_ptr[row];
    const uint4* cq = (const uint4*)(ccnt + row * CST);
    uint4 q0 = cq[0];   // chunk counts 0..7 (u16 pairs)
    uint4 q1 = cq[1];   // chunk counts 8..15
    u32 cw[8] = {q0.x, q0.y, q0.z, q0.w, q1.x, q1.y, q1.z, q1.w};
    float acc[8] = {0, 0, 0, 0, 0, 0, 0, 0};
#pragma unroll
    for (int c = 0; c < NCH; ++c) {
        int cnt = (int)((cw[c >> 1] >> ((c & 1) * 16)) & 0xffffu);
        for (int k = 0; k < cnt; ++k) {
            int nb = csr_src[pos + k];
            uint4 v = *(const uint4*)(hb + ((size_t)nb << 6) + (d4 << 3));
            acc[0] += __uint_as_float(v.x << 16);
            acc[1] += __uint_as_float(v.x & 0xffff0000u);
            acc[2] += __uint_as_float(v.y << 16);
            acc[3] += __uint_as_float(v.y & 0xffff0000u);
            acc[4] += __uint_as_float(v.z << 16);
            acc[5] += __uint_as_float(v.z & 0xffff0000u);
            acc[6] += __uint_as_float(v.w << 16);
            acc[7] += __uint_as_float(v.w & 0xffff0000u);
        }
        pos += cnt;
    }
    float di = deg_inv[row];
    uint4 p;
    p.x = pack_bf16(acc[0] * di, acc[1] * di);
    p.y = pack_bf16(acc[2] * di, acc[3] * di);
    p.z = pack_bf16(acc[4] * di, acc[5] * di);
    p.w = pack_bf16(acc[6] * di, acc[7] * di);
    *(uint4*)(Mb + ((size_t)row << 6) + (d4 << 3)) = p;
}

// ---------------- transform: C = Mb@Wn + b + Hb@Wr (+relu | +euler+traj) ----
template <int MODE>
__global__ __launch_bounds__(256) void k_transform(
        const u16* __restrict__ Mb, const u16* __restrict__ Hb,
        const float* __restrict__ Wn, const float* __restrict__ bias,
        const float* __restrict__ Wr, const float* __restrict__ prev,
        const float* __restrict__ ts, int tstep, float* __restrict__ out,
        u16* __restrict__ out_b,
        const float* __restrict__ Wd, const float* __restrict__ bd,
        float* __restrict__ traj) {
    __shared__ float Ws[128 * 64];  // 32 KB: Wn rows 0-63, Wr rows 64-127
    __shared__ float tp0[MODE ? 128 * 9 : 1];
    __shared__ float tp1[MODE ? 128 * 9 : 1];
    int tid = threadIdx.x;
    {
        const float4* wn4 = (const float4*)Wn;
        const float4* wr4 = (const float4*)Wr;
        float4* ws4 = (float4*)Ws;
        for (int i = tid; i < 2048; i += 256)
            ws4[i] = (i < 1024) ? wn4[i] : wr4[i - 1024];
    }
    __syncthreads();
    int jg = tid & 7, ng = tid >> 3;
    int nbase = blockIdx.x * 128 + ng * 4;
    int j0 = jg * 8;
    float acc[4][8];
#pragma unroll
    for (int i = 0; i < 4; ++i)
#pragma unroll
        for (int j = 0; j < 8; ++j) acc[i][j] = bias[j0 + j];
    int nidx[4];
    bool valid[4];
#pragma unroll
    for (int i = 0; i < 4; ++i) {
        int n = nbase + i;
        valid[i] = n < NN;
        nidx[i] = valid[i] ? n : 0;
    }
#pragma unroll 1
    for (int ph = 0; ph < 2; ++ph) {
        const u16* A = ph ? Hb : Mb;
        int wofs = ph ? 64 * 64 : 0;
        for (int k0 = 0; k0 < 64; k0 += 4) {
            float a[4][4];
#pragma unroll
            for (int i = 0; i < 4; ++i) {
                ushort4 r = *(const ushort4*)(A + ((size_t)nidx[i] << 6) + k0);
                a[i][0] = bf2f(r.x); a[i][1] = bf2f(r.y);
                a[i][2] = bf2f(r.z); a[i][3] = bf2f(r.w);
            }
#pragma unroll
            for (int kk = 0; kk < 4; ++kk) {
                float w[8];
                *(float4*)&w[0] = *(float4*)&Ws[wofs + (k0 + kk) * 64 + j0];
                *(float4*)&w[4] = *(float4*)&Ws[wofs + (k0 + kk) * 64 + j0 + 4];
#pragma unroll
                for (int i = 0; i < 4; ++i)
#pragma unroll
                    for (int j = 0; j < 8; ++j)
                        acc[i][j] = fmaf(a[i][kk], w[j], acc[i][j]);
            }
        }
    }
    float dt = 0.f, wd0[8], wd1[8];
    if (MODE == 1) {
        dt = ts[tstep + 1] - ts[tstep];
#pragma unroll
        for (int j = 0; j < 8; ++j) {
            wd0[j] = Wd[(j0 + j) * 2 + 0];
            wd1[j] = Wd[(j0 + j) * 2 + 1];
        }
    }
#pragma unroll
    for (int i = 0; i < 4; ++i) {
        float o[8];
        float p0 = 0.f, p1 = 0.f;
#pragma unroll
        for (int j = 0; j < 8; ++j) {
            float v = acc[i][j];
            if (MODE == 0) v = fmaxf(v, 0.f);
            else v = prev[(size_t)nidx[i] * 64 + j0 + j] + dt * v;
            o[j] = v;
            if (MODE == 1) { p0 = fmaf(v, wd0[j], p0); p1 = fmaf(v, wd1[j], p1); }
        }
        if (MODE == 1) {
            tp0[(ng * 4 + i) * 9 + jg] = p0;
            tp1[(ng * 4 + i) * 9 + jg] = p1;
        }
        if (valid[i]) {
            if (MODE == 1) {
                *(float4*)(out + (size_t)nidx[i] * 64 + j0) = *(float4*)&o[0];
                *(float4*)(out + (size_t)nidx[i] * 64 + j0 + 4) = *(float4*)&o[4];
            }
            uint4 pb;
            pb.x = pack_bf16(o[0], o[1]);
            pb.y = pack_bf16(o[2], o[3]);
            pb.z = pack_bf16(o[4], o[5]);
            pb.w = pack_bf16(o[6], o[7]);
            *(uint4*)(out_b + (size_t)nidx[i] * 64 + j0) = pb;
        }
    }
    if (MODE == 1) {
        __syncthreads();
        int node = tid >> 1, comp = tid & 1;
        const float* tp = comp ? tp1 : tp0;
        float s = bd[comp];
#pragma unroll
        for (int g = 0; g < 8; ++g) s += tp[node * 9 + g];
        int gnode = blockIdx.x * 128 + node;
        if (gnode < NN)
            traj[((size_t)(tstep + 1) * NN + gnode) * 2 + comp] = s;
    }
}

// ---------------- init: sol[0]=x, shadow=bf16(x), traj[0]=x@Wd+bd ------------
__global__ __launch_bounds__(256) void k_init(const float* __restrict__ x,
        const float* __restrict__ Wd, const float* __restrict__ bd,
        float* __restrict__ sol0, u16* __restrict__ xb,
        float* __restrict__ traj) {
    int n = blockIdx.x * blockDim.x + threadIdx.x;
    if (n >= NN) return;
    const float4* xr = (const float4*)(x + ((size_t)n << 6));
    float4* sr = (float4*)(sol0 + ((size_t)n << 6));
    uint4* br = (uint4*)(xb + ((size_t)n << 6));
    float p0 = bd[0], p1 = bd[1];
#pragma unroll
    for (int k8 = 0; k8 < 8; ++k8) {
        float4 v0 = xr[k8 * 2];
        float4 v1 = xr[k8 * 2 + 1];
        sr[k8 * 2] = v0;
        sr[k8 * 2 + 1] = v1;
        uint4 pb;
        pb.x = pack_bf16(v0.x, v0.y);
        pb.y = pack_bf16(v0.z, v0.w);
        pb.z = pack_bf16(v1.x, v1.y);
        pb.w = pack_bf16(v1.z, v1.w);
        br[k8] = pb;
        int k = k8 * 8;
        p0 = fmaf(v0.x, Wd[(k + 0) * 2], p0); p1 = fmaf(v0.x, Wd[(k + 0) * 2 + 1], p1);
        p0 = fmaf(v0.y, Wd[(k + 1) * 2], p0); p1 = fmaf(v0.y, Wd[(k + 1) * 2 + 1], p1);
        p0 = fmaf(v0.z, Wd[(k + 2) * 2], p0); p1 = fmaf(v0.z, Wd[(k + 2) * 2 + 1], p1);
        p0 = fmaf(v0.w, Wd[(k + 3) * 2], p0); p1 = fmaf(v0.w, Wd[(k + 3) * 2 + 1], p1);
        p0 = fmaf(v1.x, Wd[(k + 4) * 2], p0); p1 = fmaf(v1.x, Wd[(k + 4) * 2 + 1], p1);
        p0 = fmaf(v1.y, Wd[(k + 5) * 2], p0); p1 = fmaf(v1.y, Wd[(k + 5) * 2 + 1], p1);
        p0 = fmaf(v1.z, Wd[(k + 6) * 2], p0); p1 = fmaf(v1.z, Wd[(k + 6) * 2 + 1], p1);
        p0 = fmaf(v1.w, Wd[(k + 7) * 2], p0); p1 = fmaf(v1.w, Wd[(k + 7) * 2 + 1], p1);
    }
    traj[(size_t)n * 2 + 0] = p0;
    traj[(size_t)n * 2 + 1] = p1;
}

extern "C" void kernel_launch(void* const* d_in, const int* in_sizes, int n_in,
                              void* d_out, int out_size, void* d_ws, size_t ws_size,
                              hipStream_t stream) {
    const float* x = (const float*)d_in[0];
    const int* ei = (const int*)d_in[1];
    const float* ts = (const float*)d_in[2];
    const float* W1n = (const float*)d_in[3];
    const float* b1 = (const float*)d_in[4];
    const float* W1r = (const float*)d_in[5];
    const float* W2n = (const float*)d_in[6];
    const float* b2 = (const float*)d_in[7];
    const float* W2r = (const float*)d_in[8];
    const float* W3n = (const float*)d_in[9];
    const float* b3 = (const float*)d_in[10];
    const float* W3r = (const float*)d_in[11];
    const float* Wd = (const float*)d_in[12];
    const float* bd = (const float*)d_in[13];
    const int* src = ei;
    const int* dst = ei + NE;

    char* w = (char*)d_ws;
    int* degc = (int*)w;         w += (size_t)NN * CST * 4;
    int* row_ptr = (int*)w;      w += (size_t)(NN + 1) * 4;
    int* cursor16 = (int*)w;     w += (size_t)NN * CST * 4;
    u16* ccnt = (u16*)w;         w += (size_t)NN * CST * 2;
    float* deg_inv = (float*)w;  w += (size_t)NN * 4;
    int* bsum = (int*)w;         w += (size_t)512 * 4;
    int* bpre = (int*)w;         w += (size_t)512 * 4;
    int* csr = (int*)w;          w += (size_t)NE * 4;
    u16* Mb = (u16*)w;           w += (size_t)NN * DIM * 2;
    u16* hb0 = (u16*)w;          w += (size_t)NN * DIM * 2;  // shadow of sol(t)
    u16* hb1 = (u16*)w;          w += (size_t)NN * DIM * 2;  // shadow of h1
    u16* hb2 = (u16*)w;          w += (size_t)NN * DIM * 2;  // shadow of h2

    float* traj = (float*)d_out;
    float* sol = traj + (size_t)TT * NN * 2;

    hipMemsetAsync(degc, 0, (size_t)NN * CST * 4, stream);
    k_degc<<<(NE + 255) / 256, 256, 0, stream>>>(src, dst, degc);
    k_bsum<<<NB_SCAN, 256, 0, stream>>>(degc, bsum);
    k_scan1<<<1, 512, 0, stream>>>(bsum, bpre);
    k_rowptr<<<NB_SCAN, 256, 0, stream>>>(degc, bpre, row_ptr, cursor16, ccnt, deg_inv);
    k_fillc<<<(NE + 255) / 256, 256, 0, stream>>>(src, dst, cursor16, csr);
    k_init<<<NB_SCAN, 256, 0, stream>>>(x, Wd, bd, sol, hb0, traj);

    const int GB = NN / 32;            // 3125 blocks, 32 rows each (exact)
    const int TB = (NN + 127) / 128;   // 782 blocks
    for (int t = 0; t < TT - 1; ++t) {
        float* st = sol + (size_t)t * NN * DIM;
        float* sn = st + (size_t)NN * DIM;
        k_gather<<<GB, 256, 0, stream>>>(hb0, row_ptr, ccnt, csr, deg_inv, Mb);
        k_transform<0><<<TB, 256, 0, stream>>>(Mb, hb0, W1n, b1, W1r, nullptr,
                ts, t, nullptr, hb1, Wd, bd, traj);
        k_gather<<<GB, 256, 0, stream>>>(hb1, row_ptr, ccnt, csr, deg_inv, Mb);
        k_transform<0><<<TB, 256, 0, stream>>>(Mb, hb1, W2n, b2, W2r, nullptr,
                ts, t, nullptr, hb2, Wd, bd, traj);
        k_gather<<<GB, 256, 0, stream>>>(hb2, row_ptr, ccnt, csr, deg_inv, Mb);
        k_transform<1><<<TB, 256, 0, stream>>>(Mb, hb2, W3n, b3, W3r, st,
                ts, t, sn, hb0, Wd, bd, traj);
    }
}

// Round 8
// 2286.071 us; speedup vs baseline: 1.3464x; 1.3464x over previous
//
#include <hip/hip_runtime.h>

#define NN 100000
#define NE 1600000
#define DIM 64
#define TT 11
#define NB_SCAN 391  // ceil(NN/256)

typedef unsigned short u16;
typedef unsigned int u32;
typedef __attribute__((ext_vector_type(8))) short bf16x8;
typedef __attribute__((ext_vector_type(4))) float f32x4;

__device__ __forceinline__ u32 pack_bf16(float a, float b) {
    u32 ua = __float_as_uint(a);
    ua += 0x7fff + ((ua >> 16) & 1);
    u32 ub = __float_as_uint(b);
    ub += 0x7fff + ((ub >> 16) & 1);
    return (ua >> 16) | (ub & 0xffff0000u);
}

// ---------------- CSR build ----------------
__global__ void k_deg(const int* __restrict__ dst, int* __restrict__ deg) {
    int e = blockIdx.x * blockDim.x + threadIdx.x;
    if (e < NE) atomicAdd(&deg[dst[e]], 1);
}

__global__ __launch_bounds__(256) void k_bsum(const int* __restrict__ deg,
                                              int* __restrict__ bsum) {
    __shared__ int s[256];
    int t = threadIdx.x;
    int i = blockIdx.x * 256 + t;
    s[t] = (i < NN) ? deg[i] : 0;
    __syncthreads();
    for (int off = 128; off >= 1; off >>= 1) {
        if (t < off) s[t] += s[t + off];
        __syncthreads();
    }
    if (t == 0) bsum[blockIdx.x] = s[0];
}

__global__ __launch_bounds__(512) void k_scan1(const int* __restrict__ bsum,
                                               int* __restrict__ bpre) {
    __shared__ int s[512];
    int t = threadIdx.x;
    int v0 = (t < NB_SCAN) ? bsum[t] : 0;
    s[t] = v0;
    __syncthreads();
    for (int off = 1; off < 512; off <<= 1) {
        int v = (t >= off) ? s[t - off] : 0;
        __syncthreads();
        s[t] += v;
        __syncthreads();
    }
    if (t < NB_SCAN) bpre[t] = s[t] - v0;
}

__global__ __launch_bounds__(256) void k_rowptr(const int* __restrict__ deg,
        const int* __restrict__ bpre, int* __restrict__ row_ptr,
        int* __restrict__ cursor, float* __restrict__ deg_inv) {
    __shared__ int s[256];
    int t = threadIdx.x;
    int i = blockIdx.x * 256 + t;
    int d = (i < NN) ? deg[i] : 0;
    s[t] = d;
    __syncthreads();
    for (int off = 1; off < 256; off <<= 1) {
        int v = (t >= off) ? s[t - off] : 0;
        __syncthreads();
        s[t] += v;
        __syncthreads();
    }
    if (i < NN) {
        int excl = bpre[blockIdx.x] + s[t] - d;
        row_ptr[i] = excl;
        cursor[i] = excl;
        deg_inv[i] = d > 0 ? 1.0f / (float)d : 0.0f;
        if (i == NN - 1) row_ptr[NN] = excl + d;
    }
}

__global__ void k_fill(const int* __restrict__ src, const int* __restrict__ dst,
        int* __restrict__ cursor, int* __restrict__ csr_src) {
    int e = blockIdx.x * blockDim.x + threadIdx.x;
    if (e < NE) {
        int p = atomicAdd(&cursor[dst[e]], 1);
        csr_src[p] = src[e];
    }
}

// ---------------- weight prep: Wt[n][k] = bf16(W[k][n]), 6 matrices --------
__global__ __launch_bounds__(256) void k_wprep(
        const float* __restrict__ W1n, const float* __restrict__ W1r,
        const float* __restrict__ W2n, const float* __restrict__ W2r,
        const float* __restrict__ W3n, const float* __restrict__ W3r,
        u16* __restrict__ Wt) {
    const float* Ws[6] = {W1n, W1r, W2n, W2r, W3n, W3r};
    const float* W = Ws[blockIdx.x];
    u16* o = Wt + blockIdx.x * 4096;
    int t = threadIdx.x;
    int n = t >> 2, kg = (t & 3) * 16;
    u32 pk[8];
#pragma unroll
    for (int j = 0; j < 8; ++j)
        pk[j] = pack_bf16(W[(kg + 2 * j) * 64 + n], W[(kg + 2 * j + 1) * 64 + n]);
    *(uint4*)(o + n * 64 + kg)     = make_uint4(pk[0], pk[1], pk[2], pk[3]);
    *(uint4*)(o + n * 64 + kg + 8) = make_uint4(pk[4], pk[5], pk[6], pk[7]);
}

// ---------------- mean-aggregate from bf16 shadow -> bf16 M ----------------
// wave per node; 8 lanes x dwordx4 (8 bf16) per 128B row -> 8 rows per load
// instruction. f32 accumulate.
__global__ __launch_bounds__(256) void k_gather(const u16* __restrict__ hb,
        const int* __restrict__ row_ptr, const int* __restrict__ csr_src,
        const float* __restrict__ deg_inv, u16* __restrict__ Mb) {
    int wid = (int)((blockIdx.x * blockDim.x + threadIdx.x) >> 6);
    int lane = threadIdx.x & 63;
    if (wid >= NN) return;
    int sub = lane >> 3;  // edge slot within group of 8
    int d4 = lane & 7;    // 16B chunk within the 128B row
    int b = row_ptr[wid], e = row_ptr[wid + 1];
    float di = deg_inv[wid];
    float a0[8] = {0, 0, 0, 0, 0, 0, 0, 0};
    float a1[8] = {0, 0, 0, 0, 0, 0, 0, 0};
    int i = b;
    for (; i + 16 <= e; i += 16) {
        int n0 = csr_src[i + sub];
        int n1 = csr_src[i + 8 + sub];
        uint4 v0 = *(const uint4*)(hb + ((size_t)n0 << 6) + d4 * 8);
        uint4 v1 = *(const uint4*)(hb + ((size_t)n1 << 6) + d4 * 8);
        const u32* w0 = (const u32*)&v0;
        const u32* w1 = (const u32*)&v1;
#pragma unroll
        for (int w = 0; w < 4; ++w) {
            a0[2 * w]     += __uint_as_float(w0[w] << 16);
            a0[2 * w + 1] += __uint_as_float(w0[w] & 0xffff0000u);
            a1[2 * w]     += __uint_as_float(w1[w] << 16);
            a1[2 * w + 1] += __uint_as_float(w1[w] & 0xffff0000u);
        }
    }
    if (i + 8 <= e) {
        int n0 = csr_src[i + sub];
        uint4 v0 = *(const uint4*)(hb + ((size_t)n0 << 6) + d4 * 8);
        const u32* w0 = (const u32*)&v0;
#pragma unroll
        for (int w = 0; w < 4; ++w) {
            a0[2 * w]     += __uint_as_float(w0[w] << 16);
            a0[2 * w + 1] += __uint_as_float(w0[w] & 0xffff0000u);
        }
        i += 8;
    }
    if (sub < e - i) {
        int n1 = csr_src[i + sub];
        uint4 v1 = *(const uint4*)(hb + ((size_t)n1 << 6) + d4 * 8);
        const u32* w1 = (const u32*)&v1;
#pragma unroll
        for (int w = 0; w < 4; ++w) {
            a1[2 * w]     += __uint_as_float(w1[w] << 16);
            a1[2 * w + 1] += __uint_as_float(w1[w] & 0xffff0000u);
        }
    }
    float s[8];
#pragma unroll
    for (int k = 0; k < 8; ++k) {
        float v = a0[k] + a1[k];
        v += __shfl_xor(v, 32);
        v += __shfl_xor(v, 16);
        v += __shfl_xor(v, 8);
        s[k] = v * di;
    }
    if (lane < 8) {
        uint4 p;
        p.x = pack_bf16(s[0], s[1]);
        p.y = pack_bf16(s[2], s[3]);
        p.z = pack_bf16(s[4], s[5]);
        p.w = pack_bf16(s[6], s[7]);
        *(uint4*)(Mb + ((size_t)wid << 6) + d4 * 8) = p;
    }
}

// ---------------- MFMA transform: C = Mb@Wn + b + Hb@Wr --------------------
// block 256 = 4 waves; wave handles 32 nodes (2 row-tiles of 16), full 64 cols
// (4 col-tiles). mfma_f32_16x16x32_bf16: A[m][k] m=lane&15, k=(lane>>4)*8+i;
// B[k][n] n=lane&15 (from Wt[n][k] contiguous); D col=lane&15,
// row=(lane>>4)*4+reg. Epilogue routes through padded LDS for coalesced
// stores + fused trajectory (MODE 1).
template <int MODE>
__global__ __launch_bounds__(256) void k_transform(
        const u16* __restrict__ Mb, const u16* __restrict__ Hb,
        const u16* __restrict__ Wtn, const float* __restrict__ bias,
        const u16* __restrict__ Wtr, const float* __restrict__ prev,
        const float* __restrict__ ts, int tstep, float* __restrict__ out,
        u16* __restrict__ out_b,
        const float* __restrict__ Wd, const float* __restrict__ bd,
        float* __restrict__ traj) {
    __shared__ float Ls[4][32 * 68];  // 34.8 KB, padded stride 68
    __shared__ float WdS[128];
    int tid = threadIdx.x;
    if (MODE == 1 && tid < 128) WdS[tid] = Wd[tid];
    int wv = tid >> 6, lane = tid & 63;
    int r16 = lane & 15, kq = lane >> 4;
    int nodeW = blockIdx.x * 128 + wv * 32;
    // A row addresses (clamped)
    size_t rowA[2];
#pragma unroll
    for (int rt = 0; rt < 2; ++rt) {
        int n = nodeW + rt * 16 + r16;
        rowA[rt] = (size_t)(n < NN ? n : NN - 1) << 6;
    }
    // acc init = bias broadcast
    f32x4 acc[2][4];
#pragma unroll
    for (int ct = 0; ct < 4; ++ct) {
        float bc = bias[ct * 16 + r16];
#pragma unroll
        for (int rt = 0; rt < 2; ++rt)
            acc[rt][ct] = (f32x4){bc, bc, bc, bc};
    }
    // phase 0: A = Mb, B = Wn^T
    {
        bf16x8 a[2][2], b[4][2];
#pragma unroll
        for (int rt = 0; rt < 2; ++rt)
#pragma unroll
            for (int kh = 0; kh < 2; ++kh)
                a[rt][kh] = *(const bf16x8*)(Mb + rowA[rt] + kh * 32 + kq * 8);
#pragma unroll
        for (int ct = 0; ct < 4; ++ct)
#pragma unroll
            for (int kh = 0; kh < 2; ++kh)
                b[ct][kh] = *(const bf16x8*)(Wtn + (ct * 16 + r16) * 64 + kh * 32 + kq * 8);
#pragma unroll
        for (int rt = 0; rt < 2; ++rt)
#pragma unroll
            for (int ct = 0; ct < 4; ++ct)
#pragma unroll
                for (int kh = 0; kh < 2; ++kh)
                    acc[rt][ct] = __builtin_amdgcn_mfma_f32_16x16x32_bf16(
                        a[rt][kh], b[ct][kh], acc[rt][ct], 0, 0, 0);
    }
    // phase 1: A = Hb, B = Wr^T
    {
        bf16x8 a[2][2], b[4][2];
#pragma unroll
        for (int rt = 0; rt < 2; ++rt)
#pragma unroll
            for (int kh = 0; kh < 2; ++kh)
                a[rt][kh] = *(const bf16x8*)(Hb + rowA[rt] + kh * 32 + kq * 8);
#pragma unroll
        for (int ct = 0; ct < 4; ++ct)
#pragma unroll
            for (int kh = 0; kh < 2; ++kh)
                b[ct][kh] = *(const bf16x8*)(Wtr + (ct * 16 + r16) * 64 + kh * 32 + kq * 8);
#pragma unroll
        for (int rt = 0; rt < 2; ++rt)
#pragma unroll
            for (int ct = 0; ct < 4; ++ct)
#pragma unroll
                for (int kh = 0; kh < 2; ++kh)
                    acc[rt][ct] = __builtin_amdgcn_mfma_f32_16x16x32_bf16(
                        a[rt][kh], b[ct][kh], acc[rt][ct], 0, 0, 0);
    }
    // spill fragments to LDS: D col=lane&15, row=(lane>>4)*4+j
    float* L = Ls[wv];
#pragma unroll
    for (int rt = 0; rt < 2; ++rt)
#pragma unroll
        for (int ct = 0; ct < 4; ++ct)
#pragma unroll
            for (int j = 0; j < 4; ++j)
                L[(rt * 16 + kq * 4 + j) * 68 + ct * 16 + r16] = acc[rt][ct][j];
    __syncthreads();
    // epilogue: thread = (node_local, half-row of 32)
    int nl = tid >> 1, hf = tid & 1;
    int gnode = blockIdx.x * 128 + nl;
    const float* Lrow = &Ls[nl >> 5][(nl & 31) * 68 + hf * 32];
    float dt = 0.f;
    if (MODE == 1) dt = ts[tstep + 1] - ts[tstep];
    float v[32];
    float p0 = 0.f, p1 = 0.f;
    bool ok = gnode < NN;
    size_t gofs = ((size_t)(ok ? gnode : 0) << 6) + hf * 32;
#pragma unroll
    for (int i = 0; i < 32; ++i) {
        float x = Lrow[i];
        if (MODE == 0) x = fmaxf(x, 0.f);
        v[i] = x;
    }
    if (MODE == 1) {
#pragma unroll
        for (int i4 = 0; i4 < 8; ++i4) {
            float4 pv = *(const float4*)(prev + gofs + i4 * 4);
            v[i4 * 4 + 0] = pv.x + dt * v[i4 * 4 + 0];
            v[i4 * 4 + 1] = pv.y + dt * v[i4 * 4 + 1];
            v[i4 * 4 + 2] = pv.z + dt * v[i4 * 4 + 2];
            v[i4 * 4 + 3] = pv.w + dt * v[i4 * 4 + 3];
        }
#pragma unroll
        for (int i = 0; i < 32; ++i) {
            p0 = fmaf(v[i], WdS[(hf * 32 + i) * 2 + 0], p0);
            p1 = fmaf(v[i], WdS[(hf * 32 + i) * 2 + 1], p1);
        }
    }
    if (ok) {
        if (MODE == 1) {
#pragma unroll
            for (int i4 = 0; i4 < 8; ++i4)
                *(float4*)(out + gofs + i4 * 4) =
                    make_float4(v[i4 * 4], v[i4 * 4 + 1], v[i4 * 4 + 2], v[i4 * 4 + 3]);
        }
#pragma unroll
        for (int q = 0; q < 2; ++q) {
            uint4 pb;
            pb.x = pack_bf16(v[q * 16 + 0], v[q * 16 + 1]);
            pb.y = pack_bf16(v[q * 16 + 2], v[q * 16 + 3]);
            pb.z = pack_bf16(v[q * 16 + 4], v[q * 16 + 5]);
            pb.w = pack_bf16(v[q * 16 + 6], v[q * 16 + 7]);
            uint4 pc;
            pc.x = pack_bf16(v[q * 16 + 8], v[q * 16 + 9]);
            pc.y = pack_bf16(v[q * 16 + 10], v[q * 16 + 11]);
            pc.z = pack_bf16(v[q * 16 + 12], v[q * 16 + 13]);
            pc.w = pack_bf16(v[q * 16 + 14], v[q * 16 + 15]);
            *(uint4*)(out_b + gofs + q * 16)     = pb;
            *(uint4*)(out_b + gofs + q * 16 + 8) = pc;
        }
    }
    if (MODE == 1) {
        p0 += __shfl_xor(p0, 1);
        p1 += __shfl_xor(p1, 1);
        if (ok) {
            size_t ti = ((size_t)(tstep + 1) * NN + gnode) * 2;
            if (hf == 0) traj[ti + 0] = p0 + bd[0];
            else         traj[ti + 1] = p1 + bd[1];
        }
    }
}

// ---------------- init: sol[0]=x, shadow=bf16(x), traj[0]=x@Wd+bd ------------
__global__ __launch_bounds__(256) void k_init(const float* __restrict__ x,
        const float* __restrict__ Wd, const float* __restrict__ bd,
        float* __restrict__ sol0, u16* __restrict__ xb,
        float* __restrict__ traj) {
    int n = blockIdx.x * blockDim.x + threadIdx.x;
    if (n >= NN) return;
    const float4* xr = (const float4*)(x + ((size_t)n << 6));
    float4* sr = (float4*)(sol0 + ((size_t)n << 6));
    uint4* br = (uint4*)(xb + ((size_t)n << 6));
    float p0 = bd[0], p1 = bd[1];
#pragma unroll
    for (int k8 = 0; k8 < 8; ++k8) {
        float4 v0 = xr[k8 * 2];
        float4 v1 = xr[k8 * 2 + 1];
        sr[k8 * 2] = v0;
        sr[k8 * 2 + 1] = v1;
        uint4 pb;
        pb.x = pack_bf16(v0.x, v0.y);
        pb.y = pack_bf16(v0.z, v0.w);
        pb.z = pack_bf16(v1.x, v1.y);
        pb.w = pack_bf16(v1.z, v1.w);
        br[k8] = pb;
        int k = k8 * 8;
        p0 = fmaf(v0.x, Wd[(k + 0) * 2], p0); p1 = fmaf(v0.x, Wd[(k + 0) * 2 + 1], p1);
        p0 = fmaf(v0.y, Wd[(k + 1) * 2], p0); p1 = fmaf(v0.y, Wd[(k + 1) * 2 + 1], p1);
        p0 = fmaf(v0.z, Wd[(k + 2) * 2], p0); p1 = fmaf(v0.z, Wd[(k + 2) * 2 + 1], p1);
        p0 = fmaf(v0.w, Wd[(k + 3) * 2], p0); p1 = fmaf(v0.w, Wd[(k + 3) * 2 + 1], p1);
        p0 = fmaf(v1.x, Wd[(k + 4) * 2], p0); p1 = fmaf(v1.x, Wd[(k + 4) * 2 + 1], p1);
        p0 = fmaf(v1.y, Wd[(k + 5) * 2], p0); p1 = fmaf(v1.y, Wd[(k + 5) * 2 + 1], p1);
        p0 = fmaf(v1.z, Wd[(k + 6) * 2], p0); p1 = fmaf(v1.z, Wd[(k + 6) * 2 + 1], p1);
        p0 = fmaf(v1.w, Wd[(k + 7) * 2], p0); p1 = fmaf(v1.w, Wd[(k + 7) * 2 + 1], p1);
    }
    traj[(size_t)n * 2 + 0] = p0;
    traj[(size_t)n * 2 + 1] = p1;
}

extern "C" void kernel_launch(void* const* d_in, const int* in_sizes, int n_in,
                              void* d_out, int out_size, void* d_ws, size_t ws_size,
                              hipStream_t stream) {
    const float* x = (const float*)d_in[0];
    const int* ei = (const int*)d_in[1];
    const float* ts = (const float*)d_in[2];
    const float* W1n = (const float*)d_in[3];
    const float* b1 = (const float*)d_in[4];
    const float* W1r = (const float*)d_in[5];
    const float* W2n = (const float*)d_in[6];
    const float* b2 = (const float*)d_in[7];
    const float* W2r = (const float*)d_in[8];
    const float* W3n = (const float*)d_in[9];
    const float* b3 = (const float*)d_in[10];
    const float* W3r = (const float*)d_in[11];
    const float* Wd = (const float*)d_in[12];
    const float* bd = (const float*)d_in[13];
    const int* src = ei;
    const int* dst = ei + NE;

    char* w = (char*)d_ws;
    int* deg = (int*)w;          w += (size_t)NN * 4;
    int* row_ptr = (int*)w;      w += (size_t)(NN + 1) * 4;
    int* cursor = (int*)w;       w += (size_t)NN * 4;
    float* deg_inv = (float*)w;  w += (size_t)NN * 4;
    int* bsum = (int*)w;         w += (size_t)512 * 4;
    int* bpre = (int*)w;         w += (size_t)512 * 4;
    int* csr = (int*)w;          w += (size_t)NE * 4;
    u16* Wt = (u16*)w;           w += (size_t)6 * 4096 * 2;
    u16* Mb = (u16*)w;           w += (size_t)NN * DIM * 2;
    u16* hb0 = (u16*)w;          w += (size_t)NN * DIM * 2;  // shadow of sol(t)
    u16* hb1 = (u16*)w;          w += (size_t)NN * DIM * 2;  // shadow of h1
    u16* hb2 = (u16*)w;          w += (size_t)NN * DIM * 2;  // shadow of h2

    float* traj = (float*)d_out;
    float* sol = traj + (size_t)TT * NN * 2;

    hipMemsetAsync(deg, 0, (size_t)NN * 4, stream);
    k_deg<<<(NE + 255) / 256, 256, 0, stream>>>(dst, deg);
    k_bsum<<<NB_SCAN, 256, 0, stream>>>(deg, bsum);
    k_scan1<<<1, 512, 0, stream>>>(bsum, bpre);
    k_rowptr<<<NB_SCAN, 256, 0, stream>>>(deg, bpre, row_ptr, cursor, deg_inv);
    k_fill<<<(NE + 255) / 256, 256, 0, stream>>>(src, dst, cursor, csr);
    k_wprep<<<6, 256, 0, stream>>>(W1n, W1r, W2n, W2r, W3n, W3r, Wt);
    k_init<<<NB_SCAN, 256, 0, stream>>>(x, Wd, bd, sol, hb0, traj);

    const u16* Wt1n = Wt;
    const u16* Wt1r = Wt + 4096;
    const u16* Wt2n = Wt + 2 * 4096;
    const u16* Wt2r = Wt + 3 * 4096;
    const u16* Wt3n = Wt + 4 * 4096;
    const u16* Wt3r = Wt + 5 * 4096;

    const int GB = (NN * 64 + 255) / 256;  // wave per node
    const int TB = (NN + 127) / 128;       // 782 blocks
    for (int t = 0; t < TT - 1; ++t) {
        float* st = sol + (size_t)t * NN * DIM;
        float* sn = st + (size_t)NN * DIM;
        k_gather<<<GB, 256, 0, stream>>>(hb0, row_ptr, csr, deg_inv, Mb);
        k_transform<0><<<TB, 256, 0, stream>>>(Mb, hb0, Wt1n, b1, Wt1r, nullptr,
                ts, t, nullptr, hb1, Wd, bd, traj);
        k_gather<<<GB, 256, 0, stream>>>(hb1, row_ptr, csr, deg_inv, Mb);
        k_transform<0><<<TB, 256, 0, stream>>>(Mb, hb1, Wt2n, b2, Wt2r, nullptr,
                ts, t, nullptr, hb2, Wd, bd, traj);
        k_gather<<<GB, 256, 0, stream>>>(hb2, row_ptr, csr, deg_inv, Mb);
        k_transform<1><<<TB, 256, 0, stream>>>(Mb, hb2, Wt3n, b3, Wt3r, st,
                ts, t, sn, hb0, Wd, bd, traj);
    }
}